// Round 7
// baseline (254.584 us; speedup 1.0000x reference)
//
#include <hip/hip_runtime.h>

// Problem: B=2, S=4096, E=512, H=8, D=64, window 512->513 (HALF=256)
#define S_LEN  4096
#define NH     8
#define DH     64
#define EMB    512
#define HDIM   512
#define HALF_W 256
#define BATCH  2
#define M_ROWS (BATCH * S_LEN)  // 8192

typedef __attribute__((ext_vector_type(8))) short bf16x8;
typedef __attribute__((ext_vector_type(4))) float f32x4;

// ---------- bf16 helpers ----------
__device__ __forceinline__ float b2f(unsigned short u) {
    union { unsigned int i; float f; } v; v.i = ((unsigned int)u) << 16; return v.f;
}
__device__ __forceinline__ unsigned short f2b(float f) {
    unsigned int x = __float_as_uint(f);
    unsigned int r = (x + 0x7fffu + ((x >> 16) & 1u)) >> 16;   // RNE
    return (unsigned short)r;
}
__device__ __forceinline__ void unpack2(unsigned int u, float* d) {
    d[0] = b2f((unsigned short)(u & 0xffffu));
    d[1] = b2f((unsigned short)(u >> 16));
}
union FragU { uint4 u; bf16x8 f; };
__device__ __forceinline__ bf16x8 ldfrag(const unsigned short* p) {
    FragU x; x.u = *(const uint4*)p; return x.f;
}

// ---------- dtype detect (measured on-device: inputs fp32; bf16 fallback kept) ----------
__global__ void detect_dtype(const unsigned short* __restrict__ x, int* __restrict__ flag) {
    __shared__ int s;
    if (threadIdx.x == 0) s = 0;
    __syncthreads();
    int bad = 0;
    for (int i = threadIdx.x; i < 2048; i += 256) {
        float v = b2f(x[i]);
        if (!(fabsf(v) < 1.0e6f)) bad = 1;
    }
    if (bad) atomicOr(&s, 1);
    __syncthreads();
    if (threadIdx.x == 0) *flag = s;   // 1 = fp32 inputs, 0 = bf16 inputs
}

// ---------- weight transpose+convert: W[512][512] -> Wt[n][k] bf16 (q,k,v,o) ----------
__global__ __launch_bounds__(256) void transpose_w(
    const void* __restrict__ w0, const void* __restrict__ w1,
    const void* __restrict__ w2, const void* __restrict__ w3,
    unsigned short* __restrict__ out, const int* __restrict__ flag)
{
    __shared__ float t[32][33];
    const int z = blockIdx.z;
    const void* src = (z == 0) ? w0 : (z == 1) ? w1 : (z == 2) ? w2 : w3;
    unsigned short* dst = out + (size_t)z * EMB * EMB;
    const int k0 = blockIdx.y * 32, n0 = blockIdx.x * 32;
    const int kk = threadIdx.x >> 3;
    const int n4 = (threadIdx.x & 7) << 2;
    if (*flag) {
        float4 v = *(const float4*)((const float*)src + (size_t)(k0 + kk) * EMB + n0 + n4);
        t[kk][n4] = v.x; t[kk][n4 + 1] = v.y; t[kk][n4 + 2] = v.z; t[kk][n4 + 3] = v.w;
    } else {
        uint2 u = *(const uint2*)((const unsigned short*)src + (size_t)(k0 + kk) * EMB + n0 + n4);
        unpack2(u.x, &t[kk][n4]); unpack2(u.y, &t[kk][n4 + 2]);
    }
    __syncthreads();
    const int nn = threadIdx.x >> 3;
    const int ks = (threadIdx.x & 7) << 2;
    uint2 pk;
    pk.x = (unsigned int)f2b(t[ks + 0][nn]) | ((unsigned int)f2b(t[ks + 1][nn]) << 16);
    pk.y = (unsigned int)f2b(t[ks + 2][nn]) | ((unsigned int)f2b(t[ks + 3][nn]) << 16);
    *(uint2*)(dst + (size_t)(n0 + nn) * EMB + k0 + ks) = pk;
}

// ---------- input pre-convert: fp32 -> bf16, staged in d_out (dead until out-GEMM) ----------
__global__ __launch_bounds__(256) void convert_in(
    const void* __restrict__ xq, const void* __restrict__ xkv,
    unsigned short* __restrict__ Xc, const int* __restrict__ flag)
{
    if (!*flag) return;
    const int z = blockIdx.y;
    const float* src = (const float*)(z ? xkv : xq);
    unsigned short* dst = Xc + (size_t)z * M_ROWS * EMB;
    const size_t base = ((size_t)blockIdx.x * 256 + threadIdx.x) * 8;
    float4 a = *(const float4*)(src + base);
    float4 b = *(const float4*)(src + base + 4);
    uint4 pk;
    pk.x = (unsigned int)f2b(a.x) | ((unsigned int)f2b(a.y) << 16);
    pk.y = (unsigned int)f2b(a.z) | ((unsigned int)f2b(a.w) << 16);
    pk.z = (unsigned int)f2b(b.x) | ((unsigned int)f2b(b.y) << 16);
    pk.w = (unsigned int)f2b(b.z) | ((unsigned int)f2b(b.w) << 16);
    *(uint4*)(dst + base) = pk;
}

// ---------- MFMA GEMM core v2: 128x128 tile, BK=64, reg-prefetch pipeline ----------
// Per K-iter: {barrier, regs->LDS, barrier, issue next global loads, 32 MFMA}.
// Next-tile vmcnt wait lands at the NEXT iter's ds_write -> latency hides behind MFMA.
#define GP2 72   // shorts per LDS row (64 + 8 pad)

__device__ __forceinline__ void mgemm_core2(
    const unsigned short* __restrict__ A, const unsigned short* __restrict__ Bt,
    int m0, f32x4 (*acc)[4],
    unsigned short (*A_lds)[GP2], unsigned short (*B_lds)[GP2])
{
    const int tid  = threadIdx.x;
    const int lane = tid & 63;
    const int w    = tid >> 6;
    const int wm   = (w >> 1) << 6;
    const int wn   = (w & 1) << 6;
    const int qcol = lane & 15;
    const int quad = lane >> 4;
    const int srow = tid >> 1;          // 0..127
    const int sk   = (tid & 1) << 5;    // 0 or 32 shorts

    const unsigned short* ap = A  + (size_t)(m0 + srow) * EMB + sk;
    const unsigned short* bp = Bt + (size_t)srow * EMB + sk;

    uint4 ra[4], rb[4];
#pragma unroll
    for (int i = 0; i < 4; ++i) {
        ra[i] = *(const uint4*)(ap + i * 8);
        rb[i] = *(const uint4*)(bp + i * 8);
    }

    for (int k0 = 0; k0 < EMB; k0 += 64) {
        __syncthreads();
#pragma unroll
        for (int i = 0; i < 4; ++i) {
            *(uint4*)&A_lds[srow][sk + i * 8] = ra[i];
            *(uint4*)&B_lds[srow][sk + i * 8] = rb[i];
        }
        __syncthreads();
        if (k0 + 64 < EMB) {
#pragma unroll
            for (int i = 0; i < 4; ++i) {
                ra[i] = *(const uint4*)(ap + k0 + 64 + i * 8);
                rb[i] = *(const uint4*)(bp + k0 + 64 + i * 8);
            }
        }
#pragma unroll
        for (int kh = 0; kh < 2; ++kh) {
            bf16x8 af[4], bf[4];
#pragma unroll
            for (int i = 0; i < 4; ++i)
                af[i] = ldfrag(&A_lds[wm + (i << 4) + qcol][(kh << 5) + quad * 8]);
#pragma unroll
            for (int j = 0; j < 4; ++j)
                bf[j] = ldfrag(&B_lds[wn + (j << 4) + qcol][(kh << 5) + quad * 8]);
#pragma unroll
            for (int i = 0; i < 4; ++i)
#pragma unroll
                for (int j = 0; j < 4; ++j)
                    acc[i][j] = __builtin_amdgcn_mfma_f32_16x16x32_bf16(af[i], bf[j], acc[i][j], 0, 0, 0);
        }
    }
}

// fused QKV: 768 blocks; XCD-grouped mapping (xcd owns 8 m-tiles x all 12 n-tiles)
__global__ __launch_bounds__(256) void gemm_qkv(
    const void* __restrict__ xq, const void* __restrict__ xkv,
    const unsigned short* __restrict__ Xc, const unsigned short* __restrict__ Wt,
    unsigned short* __restrict__ Qb, unsigned short* __restrict__ Kb,
    unsigned short* __restrict__ Vtb, const int* __restrict__ flag)
{
    __shared__ unsigned short A_lds[128][GP2];
    __shared__ unsigned short B_lds[128][GP2];
    const int blk = blockIdx.x;
    const int xcd = blk & 7, idx = blk >> 3;       // XCD = blk%8 heuristic (perf-only)
    const int mi = idx / 12, ni = idx - mi * 12;   // mi 0..7, ni 0..11
    const int m0 = ((xcd << 3) + mi) << 7;
    const int n0 = ni << 7;

    const unsigned short* A;
    if (*flag) A = Xc + (n0 < 512 ? (size_t)0 : (size_t)M_ROWS * EMB);
    else       A = (const unsigned short*)(n0 < 512 ? xq : xkv);
    const unsigned short* Bt = Wt + (size_t)n0 * EMB;

    f32x4 acc[4][4];
#pragma unroll
    for (int i = 0; i < 4; ++i)
#pragma unroll
        for (int j = 0; j < 4; ++j) acc[i][j] = (f32x4){0.f, 0.f, 0.f, 0.f};

    mgemm_core2(A, Bt, m0, acc, A_lds, B_lds);

    const int lane = threadIdx.x & 63, w = threadIdx.x >> 6;
    const int wm = (w >> 1) << 6, wn = (w & 1) << 6;
    const int qcol = lane & 15, quad = lane >> 4;
    const int mode = (n0 < 512) ? 0 : (n0 < 1024) ? 1 : 2;
#pragma unroll
    for (int ms = 0; ms < 4; ++ms)
#pragma unroll
        for (int ns = 0; ns < 4; ++ns)
#pragma unroll
            for (int r = 0; r < 4; ++r) {
                const int m = m0 + wm + (ms << 4) + (quad << 2) + r;
                const int n = n0 + wn + (ns << 4) + qcol;
                const unsigned short us = f2b(acc[ms][ns][r]);
                if (mode == 0) {
                    Qb[(size_t)m * HDIM + n] = us;
                } else if (mode == 1) {
                    Kb[(size_t)m * HDIM + (n - 512)] = us;
                } else {
                    const int hd = n - 1024;
                    const int bb = m >> 12, s = m & (S_LEN - 1);
                    const int hh = hd >> 6, d = hd & 63;
                    Vtb[((size_t)((bb * NH + hh) * DH + d)) * S_LEN + s] = us;
                }
            }
}

// output projection: 256 blocks; XCD-grouped (xcd owns 8 m-tiles x 4 n-tiles)
__global__ __launch_bounds__(256) void gemm_out(
    const unsigned short* __restrict__ A, const unsigned short* __restrict__ Bt,
    void* __restrict__ C, const int* __restrict__ flag)
{
    __shared__ unsigned short A_lds[128][GP2];
    __shared__ unsigned short B_lds[128][GP2];
    const int blk = blockIdx.x;
    const int xcd = blk & 7, idx = blk >> 3;   // idx 0..31
    const int mi = idx >> 2, ni = idx & 3;
    const int m0 = ((xcd << 3) + mi) << 7;
    const int n0 = ni << 7;

    f32x4 acc[4][4];
#pragma unroll
    for (int i = 0; i < 4; ++i)
#pragma unroll
        for (int j = 0; j < 4; ++j) acc[i][j] = (f32x4){0.f, 0.f, 0.f, 0.f};

    mgemm_core2(A, Bt + (size_t)n0 * EMB, m0, acc, A_lds, B_lds);

    const int lane = threadIdx.x & 63, w = threadIdx.x >> 6;
    const int wm = (w >> 1) << 6, wn = (w & 1) << 6;
    const int qcol = lane & 15, quad = lane >> 4;
    const int fp = *flag;
#pragma unroll
    for (int ms = 0; ms < 4; ++ms)
#pragma unroll
        for (int ns = 0; ns < 4; ++ns)
#pragma unroll
            for (int r = 0; r < 4; ++r) {
                const int m = m0 + wm + (ms << 4) + (quad << 2) + r;
                const int n = n0 + wn + (ns << 4) + qcol;
                const float v = acc[ms][ns][r];
                if (fp) ((float*)C)[(size_t)m * HDIM + n] = v;
                else    ((unsigned short*)C)[(size_t)m * HDIM + n] = f2b(v);
            }
}

// ---------- MFMA flash attention v2 (unchanged from round 6 — HW-verified) ----------
__global__ __launch_bounds__(256) void attn_mfma(
    const unsigned short* __restrict__ Q,
    const unsigned short* __restrict__ Kg,
    const unsigned short* __restrict__ Vt,
    unsigned short* __restrict__ O)
{
    __shared__ __align__(16) unsigned short K_lds[64][72];
    __shared__ __align__(16) unsigned short V_lds[64][72];
    __shared__ __align__(16) unsigned short P_lds[4][16][72];

    const int tid  = threadIdx.x;
    const int lane = tid & 63;
    const int w    = tid >> 6;
    const int blk  = blockIdx.x;
    const int bh   = blk >> 6;
    const int r6   = blk & 63;
    const int tile = ((r6 & 7) << 3) | (r6 >> 3);
    const int h    = bh & (NH - 1);
    const int b    = bh >> 3;
    const int t0   = tile << 6;
    const int tq0  = t0 + (w << 4);

    const int qcol = lane & 15;
    const int quad = lane >> 4;
    const float slope = 1.0f / (float)(2 << h);

    const unsigned short* qrow = Q + (size_t)(b * S_LEN + tq0 + qcol) * HDIM + h * DH;
    const bf16x8 qf0 = ldfrag(qrow + quad * 8);
    const bf16x8 qf1 = ldfrag(qrow + 32 + quad * 8);

    f32x4 Oacc[4];
#pragma unroll
    for (int i = 0; i < 4; ++i) Oacc[i] = (f32x4){0.f, 0.f, 0.f, 0.f};
    float lsum = 0.f;

    for (int c = 0; c < 9; ++c) {
        const int j0 = t0 - HALF_W + (c << 6);
        __syncthreads();
#pragma unroll
        for (int p = 0; p < 2; ++p) {
            const int r  = (p << 5) + (tid >> 3);
            const int sg = (tid & 7) << 3;
            const int jc = min(max(j0 + r, 0), S_LEN - 1);
            *(uint4*)&K_lds[r][sg] =
                *(const uint4*)(Kg + (size_t)(b * S_LEN + jc) * HDIM + h * DH + sg);
            const int js = min(max(j0 + sg, 0), S_LEN - 8);
            *(uint4*)&V_lds[r][sg] =
                *(const uint4*)(Vt + ((size_t)((b * NH + h) * DH + r)) * S_LEN + js);
        }
        __syncthreads();

#pragma unroll
        for (int ks = 0; ks < 4; ++ks) {
            const bf16x8 kf0 = ldfrag(&K_lds[(ks << 4) + qcol][quad * 8]);
            const bf16x8 kf1 = ldfrag(&K_lds[(ks << 4) + qcol][32 + quad * 8]);
            f32x4 z = (f32x4){0.f, 0.f, 0.f, 0.f};
            z = __builtin_amdgcn_mfma_f32_16x16x32_bf16(kf0, qf0, z, 0, 0, 0);
            z = __builtin_amdgcn_mfma_f32_16x16x32_bf16(kf1, qf1, z, 0, 0, 0);
            unsigned short pb[4];
#pragma unroll
            for (int r = 0; r < 4; ++r) {
                const int j  = j0 + (ks << 4) + (quad << 2) + r;
                const int dd = (tq0 + qcol) - j;
                const bool ok = (j >= 0) && (j < S_LEN) && (dd <= HALF_W) && (dd >= -HALF_W);
                const float s = z[r] * 0.125f - slope * fabsf((float)dd);
                const float p = ok ? __expf(s - 12.0f) : 0.0f;
                lsum += p;
                pb[r] = f2b(p);
            }
            uint2 pk;
            pk.x = (unsigned int)pb[0] | ((unsigned int)pb[1] << 16);
            pk.y = (unsigned int)pb[2] | ((unsigned int)pb[3] << 16);
            *(uint2*)&P_lds[w][qcol][(ks << 4) + (quad << 2)] = pk;
        }

        const bf16x8 pf0 = ldfrag(&P_lds[w][qcol][quad * 8]);
        const bf16x8 pf1 = ldfrag(&P_lds[w][qcol][32 + quad * 8]);
#pragma unroll
        for (int ds = 0; ds < 4; ++ds) {
            const bf16x8 vf0 = ldfrag(&V_lds[(ds << 4) + qcol][quad * 8]);
            const bf16x8 vf1 = ldfrag(&V_lds[(ds << 4) + qcol][32 + quad * 8]);
            Oacc[ds] = __builtin_amdgcn_mfma_f32_16x16x32_bf16(vf0, pf0, Oacc[ds], 0, 0, 0);
            Oacc[ds] = __builtin_amdgcn_mfma_f32_16x16x32_bf16(vf1, pf1, Oacc[ds], 0, 0, 0);
        }
    }

    lsum += __shfl_xor(lsum, 16, 64);
    lsum += __shfl_xor(lsum, 32, 64);
    const float rz = 1.0f / lsum;

    unsigned short* obase = O + (size_t)(b * S_LEN + tq0 + qcol) * HDIM + h * DH;
#pragma unroll
    for (int ds = 0; ds < 4; ++ds) {
        uint2 pk;
        pk.x = (unsigned int)f2b(Oacc[ds][0] * rz) | ((unsigned int)f2b(Oacc[ds][1] * rz) << 16);
        pk.y = (unsigned int)f2b(Oacc[ds][2] * rz) | ((unsigned int)f2b(Oacc[ds][3] * rz) << 16);
        *(uint2*)(obase + (ds << 4) + (quad << 2)) = pk;
    }
}

// ---------- launch ----------
extern "C" void kernel_launch(void* const* d_in, const int* in_sizes, int n_in,
                              void* d_out, int out_size, void* d_ws, size_t ws_size,
                              hipStream_t stream) {
    const void* xq  = d_in[0];
    const void* xkv = d_in[1];
    const void* wq  = d_in[2];
    const void* wk  = d_in[3];
    const void* wv  = d_in[4];
    const void* wo  = d_in[5];

    int* flag = (int*)d_ws;
    unsigned short* Qb  = (unsigned short*)((char*)d_ws + 256);
    unsigned short* Kb  = Qb  + (size_t)M_ROWS * HDIM;
    unsigned short* Vtb = Kb  + (size_t)M_ROWS * HDIM;
    unsigned short* Wt  = Vtb + (size_t)M_ROWS * HDIM;
    unsigned short* Wto = Wt + (size_t)3 * EMB * EMB;
    unsigned short* Xc  = (unsigned short*)d_out;   // dead until gemm_out writes it

    detect_dtype<<<1, 256, 0, stream>>>((const unsigned short*)xq, flag);
    transpose_w<<<dim3(16, 16, 4), 256, 0, stream>>>(wq, wk, wv, wo, Wt, flag);
    convert_in<<<dim3(2048, 2), 256, 0, stream>>>(xq, xkv, Xc, flag);

    gemm_qkv<<<768, 256, 0, stream>>>(xq, xkv, Xc, Wt, Qb, Kb, Vtb, flag);
    attn_mfma<<<BATCH * NH * (S_LEN / 64), 256, 0, stream>>>(Qb, Kb, Vtb, Qb);
    gemm_out<<<256, 256, 0, stream>>>(Qb, Wto, d_out, flag);
}

// Round 8
// 183.320 us; speedup vs baseline: 1.3887x; 1.3887x over previous
//
#include <hip/hip_runtime.h>

// Problem: B=2, S=4096, E=512, H=8, D=64, window 512->513 (HALF=256)
#define S_LEN  4096
#define NH     8
#define DH     64
#define EMB    512
#define HDIM   512
#define HALF_W 256
#define BATCH  2
#define M_ROWS (BATCH * S_LEN)  // 8192

typedef __attribute__((ext_vector_type(8))) short bf16x8;
typedef __attribute__((ext_vector_type(4))) float f32x4;

// ---------- bf16 helpers ----------
__device__ __forceinline__ float b2f(unsigned short u) {
    union { unsigned int i; float f; } v; v.i = ((unsigned int)u) << 16; return v.f;
}
__device__ __forceinline__ unsigned short f2b(float f) {
    unsigned int x = __float_as_uint(f);
    unsigned int r = (x + 0x7fffu + ((x >> 16) & 1u)) >> 16;   // RNE
    return (unsigned short)r;
}
__device__ __forceinline__ void unpack2(unsigned int u, float* d) {
    d[0] = b2f((unsigned short)(u & 0xffffu));
    d[1] = b2f((unsigned short)(u >> 16));
}
union FragU { uint4 u; bf16x8 f; };
__device__ __forceinline__ bf16x8 ldfrag(const unsigned short* p) {
    FragU x; x.u = *(const uint4*)p; return x.f;
}

// ---------- async global->LDS, 16B per lane (m97 pattern) ----------
// HW semantics: LDS dst = wave-uniform base + lane*16; our per-lane lds ptrs
// are constructed to satisfy exactly that (unpadded rows, lane-ordered).
__device__ __forceinline__ void async16(const unsigned short* g, unsigned short* l) {
    __builtin_amdgcn_global_load_lds(
        (__attribute__((address_space(1))) void*)const_cast<unsigned short*>(g),
        (__attribute__((address_space(3))) void*)l, 16, 0, 0);
}

// ---------- dtype detect (measured on-device: inputs fp32; bf16 fallback kept) ----------
__global__ void detect_dtype(const unsigned short* __restrict__ x, int* __restrict__ flag) {
    __shared__ int s;
    if (threadIdx.x == 0) s = 0;
    __syncthreads();
    int bad = 0;
    for (int i = threadIdx.x; i < 2048; i += 256) {
        float v = b2f(x[i]);
        if (!(fabsf(v) < 1.0e6f)) bad = 1;
    }
    if (bad) atomicOr(&s, 1);
    __syncthreads();
    if (threadIdx.x == 0) *flag = s;   // 1 = fp32 inputs, 0 = bf16 inputs
}

// ---------- weight transpose+convert: W[512][512] -> Wt[n][k] bf16 (q,k,v,o) ----------
__global__ __launch_bounds__(256) void transpose_w(
    const void* __restrict__ w0, const void* __restrict__ w1,
    const void* __restrict__ w2, const void* __restrict__ w3,
    unsigned short* __restrict__ out, const int* __restrict__ flag)
{
    __shared__ float t[32][33];
    const int z = blockIdx.z;
    const void* src = (z == 0) ? w0 : (z == 1) ? w1 : (z == 2) ? w2 : w3;
    unsigned short* dst = out + (size_t)z * EMB * EMB;
    const int k0 = blockIdx.y * 32, n0 = blockIdx.x * 32;
    const int kk = threadIdx.x >> 3;
    const int n4 = (threadIdx.x & 7) << 2;
    if (*flag) {
        float4 v = *(const float4*)((const float*)src + (size_t)(k0 + kk) * EMB + n0 + n4);
        t[kk][n4] = v.x; t[kk][n4 + 1] = v.y; t[kk][n4 + 2] = v.z; t[kk][n4 + 3] = v.w;
    } else {
        uint2 u = *(const uint2*)((const unsigned short*)src + (size_t)(k0 + kk) * EMB + n0 + n4);
        unpack2(u.x, &t[kk][n4]); unpack2(u.y, &t[kk][n4 + 2]);
    }
    __syncthreads();
    const int nn = threadIdx.x >> 3;
    const int ks = (threadIdx.x & 7) << 2;
    uint2 pk;
    pk.x = (unsigned int)f2b(t[ks + 0][nn]) | ((unsigned int)f2b(t[ks + 1][nn]) << 16);
    pk.y = (unsigned int)f2b(t[ks + 2][nn]) | ((unsigned int)f2b(t[ks + 3][nn]) << 16);
    *(uint2*)(dst + (size_t)(n0 + nn) * EMB + k0 + ks) = pk;
}

// ---------- input pre-convert: fp32 -> bf16, staged in d_out (dead until out-GEMM) ----------
__global__ __launch_bounds__(256) void convert_in(
    const void* __restrict__ xq, const void* __restrict__ xkv,
    unsigned short* __restrict__ Xc, const int* __restrict__ flag)
{
    if (!*flag) return;
    const int z = blockIdx.y;
    const float* src = (const float*)(z ? xkv : xq);
    unsigned short* dst = Xc + (size_t)z * M_ROWS * EMB;
    const size_t base = ((size_t)blockIdx.x * 256 + threadIdx.x) * 8;
    float4 a = *(const float4*)(src + base);
    float4 b = *(const float4*)(src + base + 4);
    uint4 pk;
    pk.x = (unsigned int)f2b(a.x) | ((unsigned int)f2b(a.y) << 16);
    pk.y = (unsigned int)f2b(a.z) | ((unsigned int)f2b(a.w) << 16);
    pk.z = (unsigned int)f2b(b.x) | ((unsigned int)f2b(b.y) << 16);
    pk.w = (unsigned int)f2b(b.z) | ((unsigned int)f2b(b.w) << 16);
    *(uint4*)(dst + base) = pk;
}

// ---------- MFMA GEMM core v3 (m97 structure): BK=32, global_load_lds, no staging VGPRs ----------
// Unpadded LDS rows (required by global_load_lds lane-ordering; also bank-optimal:
// 64B rows alternate bank halves). Per K-iter: {sync; 4x async16; sync(vmcnt drain);
// 8x ds_read_b128 + 16 MFMA}. Latency hidden by ~3 co-resident blocks/CU (m97-style).
__device__ __forceinline__ void mgemm_core3(
    const unsigned short* __restrict__ A, const unsigned short* __restrict__ Bt,
    int m0, f32x4 (*acc)[4],
    unsigned short (*A_lds)[32], unsigned short (*B_lds)[32])
{
    const int tid  = threadIdx.x;
    const int lane = tid & 63;
    const int w    = tid >> 6;
    const int wm   = (w >> 1) << 6;
    const int wn   = (w & 1) << 6;
    const int qcol = lane & 15;
    const int quad = lane >> 4;

    // staging coords: wave w covers rows w*16+(lane>>2), 16B seg (lane&3)*8
    const int arow = (w << 4) + (lane >> 2);
    const int acol = (lane & 3) << 3;

    const unsigned short* gA = A  + (size_t)(m0 + arow) * EMB + acol;
    const unsigned short* gB = Bt + (size_t)arow * EMB + acol;
    unsigned short* lA0 = &A_lds[arow][acol];        // = wave base + lane*16
    unsigned short* lA1 = &A_lds[64 + arow][acol];
    unsigned short* lB0 = &B_lds[arow][acol];
    unsigned short* lB1 = &B_lds[64 + arow][acol];
    const size_t half = (size_t)64 * EMB;

    for (int k0 = 0; k0 < EMB; k0 += 32) {
        __syncthreads();                 // previous iter's frag reads complete
        async16(gA + k0, lA0);
        async16(gA + half + k0, lA1);
        async16(gB + k0, lB0);
        async16(gB + half + k0, lB1);
        __syncthreads();                 // vmcnt(0) drain -> LDS visible

        bf16x8 af[4], bf[4];
#pragma unroll
        for (int i = 0; i < 4; ++i) af[i] = ldfrag(&A_lds[wm + (i << 4) + qcol][quad * 8]);
#pragma unroll
        for (int j = 0; j < 4; ++j) bf[j] = ldfrag(&B_lds[wn + (j << 4) + qcol][quad * 8]);
#pragma unroll
        for (int i = 0; i < 4; ++i)
#pragma unroll
            for (int j = 0; j < 4; ++j)
                acc[i][j] = __builtin_amdgcn_mfma_f32_16x16x32_bf16(af[i], bf[j], acc[i][j], 0, 0, 0);
    }
}

// fused QKV: 768 blocks; XCD-grouped mapping (xcd owns 8 m-tiles x all 12 n-tiles)
__global__ __launch_bounds__(256) void gemm_qkv(
    const void* __restrict__ xq, const void* __restrict__ xkv,
    const unsigned short* __restrict__ Xc, const unsigned short* __restrict__ Wt,
    unsigned short* __restrict__ Qb, unsigned short* __restrict__ Kb,
    unsigned short* __restrict__ Vtb, const int* __restrict__ flag)
{
    __shared__ __align__(16) unsigned short A_lds[128][32];
    __shared__ __align__(16) unsigned short B_lds[128][32];
    const int blk = blockIdx.x;
    const int xcd = blk & 7, idx = blk >> 3;       // XCD = blk%8 heuristic (perf-only)
    const int mi = idx / 12, ni = idx - mi * 12;   // mi 0..7, ni 0..11
    const int m0 = ((xcd << 3) + mi) << 7;
    const int n0 = ni << 7;

    const unsigned short* A;
    if (*flag) A = Xc + (n0 < 512 ? (size_t)0 : (size_t)M_ROWS * EMB);
    else       A = (const unsigned short*)(n0 < 512 ? xq : xkv);
    const unsigned short* Bt = Wt + (size_t)n0 * EMB;

    f32x4 acc[4][4];
#pragma unroll
    for (int i = 0; i < 4; ++i)
#pragma unroll
        for (int j = 0; j < 4; ++j) acc[i][j] = (f32x4){0.f, 0.f, 0.f, 0.f};

    mgemm_core3(A, Bt, m0, acc, A_lds, B_lds);

    const int lane = threadIdx.x & 63, w = threadIdx.x >> 6;
    const int wm = (w >> 1) << 6, wn = (w & 1) << 6;
    const int qcol = lane & 15, quad = lane >> 4;
    const int mode = (n0 < 512) ? 0 : (n0 < 1024) ? 1 : 2;
#pragma unroll
    for (int ms = 0; ms < 4; ++ms)
#pragma unroll
        for (int ns = 0; ns < 4; ++ns)
#pragma unroll
            for (int r = 0; r < 4; ++r) {
                const int m = m0 + wm + (ms << 4) + (quad << 2) + r;
                const int n = n0 + wn + (ns << 4) + qcol;
                const unsigned short us = f2b(acc[ms][ns][r]);
                if (mode == 0) {
                    Qb[(size_t)m * HDIM + n] = us;
                } else if (mode == 1) {
                    Kb[(size_t)m * HDIM + (n - 512)] = us;
                } else {
                    const int hd = n - 1024;
                    const int bb = m >> 12, s = m & (S_LEN - 1);
                    const int hh = hd >> 6, d = hd & 63;
                    Vtb[((size_t)((bb * NH + hh) * DH + d)) * S_LEN + s] = us;
                }
            }
}

// output projection: 256 blocks; XCD-grouped (xcd owns 8 m-tiles x 4 n-tiles)
__global__ __launch_bounds__(256) void gemm_out(
    const unsigned short* __restrict__ A, const unsigned short* __restrict__ Bt,
    void* __restrict__ C, const int* __restrict__ flag)
{
    __shared__ __align__(16) unsigned short A_lds[128][32];
    __shared__ __align__(16) unsigned short B_lds[128][32];
    const int blk = blockIdx.x;
    const int xcd = blk & 7, idx = blk >> 3;   // idx 0..31
    const int mi = idx >> 2, ni = idx & 3;
    const int m0 = ((xcd << 3) + mi) << 7;
    const int n0 = ni << 7;

    f32x4 acc[4][4];
#pragma unroll
    for (int i = 0; i < 4; ++i)
#pragma unroll
        for (int j = 0; j < 4; ++j) acc[i][j] = (f32x4){0.f, 0.f, 0.f, 0.f};

    mgemm_core3(A, Bt + (size_t)n0 * EMB, m0, acc, A_lds, B_lds);

    const int lane = threadIdx.x & 63, w = threadIdx.x >> 6;
    const int wm = (w >> 1) << 6, wn = (w & 1) << 6;
    const int qcol = lane & 15, quad = lane >> 4;
    const int fp = *flag;
#pragma unroll
    for (int ms = 0; ms < 4; ++ms)
#pragma unroll
        for (int ns = 0; ns < 4; ++ns)
#pragma unroll
            for (int r = 0; r < 4; ++r) {
                const int m = m0 + wm + (ms << 4) + (quad << 2) + r;
                const int n = n0 + wn + (ns << 4) + qcol;
                const float v = acc[ms][ns][r];
                if (fp) ((float*)C)[(size_t)m * HDIM + n] = v;
                else    ((unsigned short*)C)[(size_t)m * HDIM + n] = f2b(v);
            }
}

// ---------- MFMA flash attention v2 (unchanged — HW-verified) ----------
__global__ __launch_bounds__(256) void attn_mfma(
    const unsigned short* __restrict__ Q,
    const unsigned short* __restrict__ Kg,
    const unsigned short* __restrict__ Vt,
    unsigned short* __restrict__ O)
{
    __shared__ __align__(16) unsigned short K_lds[64][72];
    __shared__ __align__(16) unsigned short V_lds[64][72];
    __shared__ __align__(16) unsigned short P_lds[4][16][72];

    const int tid  = threadIdx.x;
    const int lane = tid & 63;
    const int w    = tid >> 6;
    const int blk  = blockIdx.x;
    const int bh   = blk >> 6;
    const int r6   = blk & 63;
    const int tile = ((r6 & 7) << 3) | (r6 >> 3);
    const int h    = bh & (NH - 1);
    const int b    = bh >> 3;
    const int t0   = tile << 6;
    const int tq0  = t0 + (w << 4);

    const int qcol = lane & 15;
    const int quad = lane >> 4;
    const float slope = 1.0f / (float)(2 << h);

    const unsigned short* qrow = Q + (size_t)(b * S_LEN + tq0 + qcol) * HDIM + h * DH;
    const bf16x8 qf0 = ldfrag(qrow + quad * 8);
    const bf16x8 qf1 = ldfrag(qrow + 32 + quad * 8);

    f32x4 Oacc[4];
#pragma unroll
    for (int i = 0; i < 4; ++i) Oacc[i] = (f32x4){0.f, 0.f, 0.f, 0.f};
    float lsum = 0.f;

    for (int c = 0; c < 9; ++c) {
        const int j0 = t0 - HALF_W + (c << 6);
        __syncthreads();
#pragma unroll
        for (int p = 0; p < 2; ++p) {
            const int r  = (p << 5) + (tid >> 3);
            const int sg = (tid & 7) << 3;
            const int jc = min(max(j0 + r, 0), S_LEN - 1);
            *(uint4*)&K_lds[r][sg] =
                *(const uint4*)(Kg + (size_t)(b * S_LEN + jc) * HDIM + h * DH + sg);
            const int js = min(max(j0 + sg, 0), S_LEN - 8);
            *(uint4*)&V_lds[r][sg] =
                *(const uint4*)(Vt + ((size_t)((b * NH + h) * DH + r)) * S_LEN + js);
        }
        __syncthreads();

#pragma unroll
        for (int ks = 0; ks < 4; ++ks) {
            const bf16x8 kf0 = ldfrag(&K_lds[(ks << 4) + qcol][quad * 8]);
            const bf16x8 kf1 = ldfrag(&K_lds[(ks << 4) + qcol][32 + quad * 8]);
            f32x4 z = (f32x4){0.f, 0.f, 0.f, 0.f};
            z = __builtin_amdgcn_mfma_f32_16x16x32_bf16(kf0, qf0, z, 0, 0, 0);
            z = __builtin_amdgcn_mfma_f32_16x16x32_bf16(kf1, qf1, z, 0, 0, 0);
            unsigned short pb[4];
#pragma unroll
            for (int r = 0; r < 4; ++r) {
                const int j  = j0 + (ks << 4) + (quad << 2) + r;
                const int dd = (tq0 + qcol) - j;
                const bool ok = (j >= 0) && (j < S_LEN) && (dd <= HALF_W) && (dd >= -HALF_W);
                const float s = z[r] * 0.125f - slope * fabsf((float)dd);
                const float p = ok ? __expf(s - 12.0f) : 0.0f;
                lsum += p;
                pb[r] = f2b(p);
            }
            uint2 pk;
            pk.x = (unsigned int)pb[0] | ((unsigned int)pb[1] << 16);
            pk.y = (unsigned int)pb[2] | ((unsigned int)pb[3] << 16);
            *(uint2*)&P_lds[w][qcol][(ks << 4) + (quad << 2)] = pk;
        }

        const bf16x8 pf0 = ldfrag(&P_lds[w][qcol][quad * 8]);
        const bf16x8 pf1 = ldfrag(&P_lds[w][qcol][32 + quad * 8]);
#pragma unroll
        for (int ds = 0; ds < 4; ++ds) {
            const bf16x8 vf0 = ldfrag(&V_lds[(ds << 4) + qcol][quad * 8]);
            const bf16x8 vf1 = ldfrag(&V_lds[(ds << 4) + qcol][32 + quad * 8]);
            Oacc[ds] = __builtin_amdgcn_mfma_f32_16x16x32_bf16(vf0, pf0, Oacc[ds], 0, 0, 0);
            Oacc[ds] = __builtin_amdgcn_mfma_f32_16x16x32_bf16(vf1, pf1, Oacc[ds], 0, 0, 0);
        }
    }

    lsum += __shfl_xor(lsum, 16, 64);
    lsum += __shfl_xor(lsum, 32, 64);
    const float rz = 1.0f / lsum;

    unsigned short* obase = O + (size_t)(b * S_LEN + tq0 + qcol) * HDIM + h * DH;
#pragma unroll
    for (int ds = 0; ds < 4; ++ds) {
        uint2 pk;
        pk.x = (unsigned int)f2b(Oacc[ds][0] * rz) | ((unsigned int)f2b(Oacc[ds][1] * rz) << 16);
        pk.y = (unsigned int)f2b(Oacc[ds][2] * rz) | ((unsigned int)f2b(Oacc[ds][3] * rz) << 16);
        *(uint2*)(obase + (ds << 4) + (quad << 2)) = pk;
    }
}

// ---------- launch ----------
extern "C" void kernel_launch(void* const* d_in, const int* in_sizes, int n_in,
                              void* d_out, int out_size, void* d_ws, size_t ws_size,
                              hipStream_t stream) {
    const void* xq  = d_in[0];
    const void* xkv = d_in[1];
    const void* wq  = d_in[2];
    const void* wk  = d_in[3];
    const void* wv  = d_in[4];
    const void* wo  = d_in[5];

    int* flag = (int*)d_ws;
    unsigned short* Qb  = (unsigned short*)((char*)d_ws + 256);
    unsigned short* Kb  = Qb  + (size_t)M_ROWS * HDIM;
    unsigned short* Vtb = Kb  + (size_t)M_ROWS * HDIM;
    unsigned short* Wt  = Vtb + (size_t)M_ROWS * HDIM;
    unsigned short* Wto = Wt + (size_t)3 * EMB * EMB;
    unsigned short* Xc  = (unsigned short*)d_out;   // dead until gemm_out writes it

    detect_dtype<<<1, 256, 0, stream>>>((const unsigned short*)xq, flag);
    transpose_w<<<dim3(16, 16, 4), 256, 0, stream>>>(wq, wk, wv, wo, Wt, flag);
    convert_in<<<dim3(2048, 2), 256, 0, stream>>>(xq, xkv, Xc, flag);

    gemm_qkv<<<768, 256, 0, stream>>>(xq, xkv, Xc, Wt, Qb, Kb, Vtb, flag);
    attn_mfma<<<BATCH * NH * (S_LEN / 64), 256, 0, stream>>>(Qb, Kb, Vtb, Qb);
    gemm_out<<<256, 256, 0, stream>>>(Qb, Wto, d_out, flag);
}

// Round 9
// 170.867 us; speedup vs baseline: 1.4900x; 1.0729x over previous
//
#include <hip/hip_runtime.h>

// Problem: B=2, S=4096, E=512, H=8, D=64, window 512->513 (HALF=256)
#define S_LEN  4096
#define NH     8
#define DH     64
#define EMB    512
#define HDIM   512
#define HALF_W 256
#define BATCH  2
#define M_ROWS (BATCH * S_LEN)  // 8192

typedef __attribute__((ext_vector_type(8))) short bf16x8;
typedef __attribute__((ext_vector_type(4))) float f32x4;

// ---------- bf16 helpers ----------
__device__ __forceinline__ float b2f(unsigned short u) {
    union { unsigned int i; float f; } v; v.i = ((unsigned int)u) << 16; return v.f;
}
__device__ __forceinline__ unsigned short f2b(float f) {
    unsigned int x = __float_as_uint(f);
    unsigned int r = (x + 0x7fffu + ((x >> 16) & 1u)) >> 16;   // RNE
    return (unsigned short)r;
}
__device__ __forceinline__ void unpack2(unsigned int u, float* d) {
    d[0] = b2f((unsigned short)(u & 0xffffu));
    d[1] = b2f((unsigned short)(u >> 16));
}
union FragU { uint4 u; bf16x8 f; };
__device__ __forceinline__ bf16x8 ldfrag(const unsigned short* p) {
    FragU x; x.u = *(const uint4*)p; return x.f;
}

// ---------- async global->LDS, 16B per lane (m97 pattern) ----------
__device__ __forceinline__ void async16(const unsigned short* g, unsigned short* l) {
    __builtin_amdgcn_global_load_lds(
        (__attribute__((address_space(1))) void*)const_cast<unsigned short*>(g),
        (__attribute__((address_space(3))) void*)l, 16, 0, 0);
}

// ---------- dtype detect (measured on-device: inputs fp32; bf16 fallback kept) ----------
__global__ void detect_dtype(const unsigned short* __restrict__ x, int* __restrict__ flag) {
    __shared__ int s;
    if (threadIdx.x == 0) s = 0;
    __syncthreads();
    int bad = 0;
    for (int i = threadIdx.x; i < 2048; i += 256) {
        float v = b2f(x[i]);
        if (!(fabsf(v) < 1.0e6f)) bad = 1;
    }
    if (bad) atomicOr(&s, 1);
    __syncthreads();
    if (threadIdx.x == 0) *flag = s;   // 1 = fp32 inputs, 0 = bf16 inputs
}

// ---------- weight transpose+convert: W[512][512] -> Wt[n][k] bf16 (q,k,v,o) ----------
__global__ __launch_bounds__(256) void transpose_w(
    const void* __restrict__ w0, const void* __restrict__ w1,
    const void* __restrict__ w2, const void* __restrict__ w3,
    unsigned short* __restrict__ out, const int* __restrict__ flag)
{
    __shared__ float t[32][33];
    const int z = blockIdx.z;
    const void* src = (z == 0) ? w0 : (z == 1) ? w1 : (z == 2) ? w2 : w3;
    unsigned short* dst = out + (size_t)z * EMB * EMB;
    const int k0 = blockIdx.y * 32, n0 = blockIdx.x * 32;
    const int kk = threadIdx.x >> 3;
    const int n4 = (threadIdx.x & 7) << 2;
    if (*flag) {
        float4 v = *(const float4*)((const float*)src + (size_t)(k0 + kk) * EMB + n0 + n4);
        t[kk][n4] = v.x; t[kk][n4 + 1] = v.y; t[kk][n4 + 2] = v.z; t[kk][n4 + 3] = v.w;
    } else {
        uint2 u = *(const uint2*)((const unsigned short*)src + (size_t)(k0 + kk) * EMB + n0 + n4);
        unpack2(u.x, &t[kk][n4]); unpack2(u.y, &t[kk][n4 + 2]);
    }
    __syncthreads();
    const int nn = threadIdx.x >> 3;
    const int ks = (threadIdx.x & 7) << 2;
    uint2 pk;
    pk.x = (unsigned int)f2b(t[ks + 0][nn]) | ((unsigned int)f2b(t[ks + 1][nn]) << 16);
    pk.y = (unsigned int)f2b(t[ks + 2][nn]) | ((unsigned int)f2b(t[ks + 3][nn]) << 16);
    *(uint2*)(dst + (size_t)(n0 + nn) * EMB + k0 + ks) = pk;
}

// ---------- input pre-convert: fp32 -> bf16, staged in d_out (dead until out-GEMM) ----------
__global__ __launch_bounds__(256) void convert_in(
    const void* __restrict__ xq, const void* __restrict__ xkv,
    unsigned short* __restrict__ Xc, const int* __restrict__ flag)
{
    if (!*flag) return;
    const int z = blockIdx.y;
    const float* src = (const float*)(z ? xkv : xq);
    unsigned short* dst = Xc + (size_t)z * M_ROWS * EMB;
    const size_t base = ((size_t)blockIdx.x * 256 + threadIdx.x) * 8;
    float4 a = *(const float4*)(src + base);
    float4 b = *(const float4*)(src + base + 4);
    uint4 pk;
    pk.x = (unsigned int)f2b(a.x) | ((unsigned int)f2b(a.y) << 16);
    pk.y = (unsigned int)f2b(a.z) | ((unsigned int)f2b(a.w) << 16);
    pk.z = (unsigned int)f2b(b.x) | ((unsigned int)f2b(b.y) << 16);
    pk.w = (unsigned int)f2b(b.z) | ((unsigned int)f2b(b.w) << 16);
    *(uint4*)(dst + base) = pk;
}

// ---------- MFMA GEMM core v4: 128x64 tile, BK=64, async + XOR-swizzled LDS ----------
// Segment s (16B) of row r stored at position p = s ^ (r&7): wave-uniform async dst
// (base + lane*16) preserved, fragment ds_read_b128 spread 8/bank (2-way = free).
// 8 K-iters; 16 MFMA + 12 ds_read_b128 per iter per wave; acc 32 AGPR; LDS 24KB.
__device__ __forceinline__ void mgemm_core4(
    const unsigned short* __restrict__ A, const unsigned short* __restrict__ Bt,
    int m0, f32x4 (*acc)[2],
    unsigned short (*A_lds)[64], unsigned short (*B_lds)[64])
{
    const int tid  = threadIdx.x;
    const int lane = tid & 63;
    const int w    = tid >> 6;
    const int wm   = (w >> 1) << 6;     // 0 / 64
    const int wn   = (w & 1) << 5;      // 0 / 32
    const int qcol = lane & 15;
    const int quad = lane >> 4;

    const int srow = tid >> 3;          // 0..31
    const int sp   = tid & 7;           // LDS segment position

    for (int k0 = 0; k0 < EMB; k0 += 64) {
        __syncthreads();                // previous iter's frag reads complete
#pragma unroll
        for (int i = 0; i < 4; ++i) {
            const int row  = (i << 5) + srow;            // 0..127
            const int gcol = ((sp ^ (row & 7)) << 3);    // gather-swizzle
            async16(A + (size_t)(m0 + row) * EMB + k0 + gcol, &A_lds[row][sp << 3]);
        }
#pragma unroll
        for (int i = 0; i < 2; ++i) {
            const int row  = (i << 5) + srow;            // 0..63
            const int gcol = ((sp ^ (row & 7)) << 3);
            async16(Bt + (size_t)row * EMB + k0 + gcol, &B_lds[row][sp << 3]);
        }
        __syncthreads();                // drain -> LDS visible

#pragma unroll
        for (int kh = 0; kh < 2; ++kh) {
            bf16x8 af[4], bf[2];
#pragma unroll
            for (int i = 0; i < 4; ++i) {
                const int row = wm + (i << 4) + qcol;
                const int p   = ((kh << 2) + quad) ^ (row & 7);
                af[i] = ldfrag(&A_lds[row][p << 3]);
            }
#pragma unroll
            for (int j = 0; j < 2; ++j) {
                const int row = wn + (j << 4) + qcol;
                const int p   = ((kh << 2) + quad) ^ (row & 7);
                bf[j] = ldfrag(&B_lds[row][p << 3]);
            }
#pragma unroll
            for (int i = 0; i < 4; ++i)
#pragma unroll
                for (int j = 0; j < 2; ++j)
                    acc[i][j] = __builtin_amdgcn_mfma_f32_16x16x32_bf16(af[i], bf[j], acc[i][j], 0, 0, 0);
        }
    }
}

// fused QKV: 1536 blocks; XCD-grouped (xcd owns 8 m-tiles x all 24 n-tiles)
__global__ __launch_bounds__(256) void gemm_qkv(
    const void* __restrict__ xq, const void* __restrict__ xkv,
    const unsigned short* __restrict__ Xc, const unsigned short* __restrict__ Wt,
    unsigned short* __restrict__ Qb, unsigned short* __restrict__ Kb,
    unsigned short* __restrict__ Vtb, const int* __restrict__ flag)
{
    __shared__ __align__(16) unsigned short A_lds[128][64];
    __shared__ __align__(16) unsigned short B_lds[64][64];
    const int blk = blockIdx.x;
    const int xcd = blk & 7, idx = blk >> 3;       // XCD = blk%8 heuristic (perf-only)
    const int mi = idx / 24, ni = idx - mi * 24;   // mi 0..7, ni 0..23
    const int m0 = ((xcd << 3) + mi) << 7;
    const int n0 = ni << 6;

    const unsigned short* A;
    if (*flag) A = Xc + (n0 < 512 ? (size_t)0 : (size_t)M_ROWS * EMB);
    else       A = (const unsigned short*)(n0 < 512 ? xq : xkv);
    const unsigned short* Bt = Wt + (size_t)n0 * EMB;

    f32x4 acc[4][2];
#pragma unroll
    for (int i = 0; i < 4; ++i)
#pragma unroll
        for (int j = 0; j < 2; ++j) acc[i][j] = (f32x4){0.f, 0.f, 0.f, 0.f};

    mgemm_core4(A, Bt, m0, acc, A_lds, B_lds);

    const int lane = threadIdx.x & 63, w = threadIdx.x >> 6;
    const int wm = (w >> 1) << 6, wn = (w & 1) << 5;
    const int qcol = lane & 15, quad = lane >> 4;
    const int mode = n0 >> 9;   // 0=Q, 1=K, 2=V
#pragma unroll
    for (int ms = 0; ms < 4; ++ms)
#pragma unroll
        for (int ns = 0; ns < 2; ++ns)
#pragma unroll
            for (int r = 0; r < 4; ++r) {
                const int m = m0 + wm + (ms << 4) + (quad << 2) + r;
                const int n = n0 + wn + (ns << 4) + qcol;
                const unsigned short us = f2b(acc[ms][ns][r]);
                if (mode == 0) {
                    Qb[(size_t)m * HDIM + n] = us;
                } else if (mode == 1) {
                    Kb[(size_t)m * HDIM + (n - 512)] = us;
                } else {
                    const int hd = n - 1024;
                    const int bb = m >> 12, s = m & (S_LEN - 1);
                    const int hh = hd >> 6, d = hd & 63;
                    Vtb[((size_t)((bb * NH + hh) * DH + d)) * S_LEN + s] = us;
                }
            }
}

// output projection: 512 blocks; XCD-grouped (xcd owns 8 m-tiles x 8 n-tiles)
__global__ __launch_bounds__(256) void gemm_out(
    const unsigned short* __restrict__ A, const unsigned short* __restrict__ Bt,
    void* __restrict__ C, const int* __restrict__ flag)
{
    __shared__ __align__(16) unsigned short A_lds[128][64];
    __shared__ __align__(16) unsigned short B_lds[64][64];
    const int blk = blockIdx.x;
    const int xcd = blk & 7, idx = blk >> 3;   // idx 0..63
    const int mi = idx >> 3, ni = idx & 7;
    const int m0 = ((xcd << 3) + mi) << 7;
    const int n0 = ni << 6;

    f32x4 acc[4][2];
#pragma unroll
    for (int i = 0; i < 4; ++i)
#pragma unroll
        for (int j = 0; j < 2; ++j) acc[i][j] = (f32x4){0.f, 0.f, 0.f, 0.f};

    mgemm_core4(A, Bt + (size_t)n0 * EMB, m0, acc, A_lds, B_lds);

    const int lane = threadIdx.x & 63, w = threadIdx.x >> 6;
    const int wm = (w >> 1) << 6, wn = (w & 1) << 5;
    const int qcol = lane & 15, quad = lane >> 4;
    const int fp = *flag;
#pragma unroll
    for (int ms = 0; ms < 4; ++ms)
#pragma unroll
        for (int ns = 0; ns < 2; ++ns)
#pragma unroll
            for (int r = 0; r < 4; ++r) {
                const int m = m0 + wm + (ms << 4) + (quad << 2) + r;
                const int n = n0 + wn + (ns << 4) + qcol;
                const float v = acc[ms][ns][r];
                if (fp) ((float*)C)[(size_t)m * HDIM + n] = v;
                else    ((unsigned short*)C)[(size_t)m * HDIM + n] = f2b(v);
            }
}

// ---------- MFMA flash attention v2 (unchanged — HW-verified) ----------
__global__ __launch_bounds__(256) void attn_mfma(
    const unsigned short* __restrict__ Q,
    const unsigned short* __restrict__ Kg,
    const unsigned short* __restrict__ Vt,
    unsigned short* __restrict__ O)
{
    __shared__ __align__(16) unsigned short K_lds[64][72];
    __shared__ __align__(16) unsigned short V_lds[64][72];
    __shared__ __align__(16) unsigned short P_lds[4][16][72];

    const int tid  = threadIdx.x;
    const int lane = tid & 63;
    const int w    = tid >> 6;
    const int blk  = blockIdx.x;
    const int bh   = blk >> 6;
    const int r6   = blk & 63;
    const int tile = ((r6 & 7) << 3) | (r6 >> 3);
    const int h    = bh & (NH - 1);
    const int b    = bh >> 3;
    const int t0   = tile << 6;
    const int tq0  = t0 + (w << 4);

    const int qcol = lane & 15;
    const int quad = lane >> 4;
    const float slope = 1.0f / (float)(2 << h);

    const unsigned short* qrow = Q + (size_t)(b * S_LEN + tq0 + qcol) * HDIM + h * DH;
    const bf16x8 qf0 = ldfrag(qrow + quad * 8);
    const bf16x8 qf1 = ldfrag(qrow + 32 + quad * 8);

    f32x4 Oacc[4];
#pragma unroll
    for (int i = 0; i < 4; ++i) Oacc[i] = (f32x4){0.f, 0.f, 0.f, 0.f};
    float lsum = 0.f;

    for (int c = 0; c < 9; ++c) {
        const int j0 = t0 - HALF_W + (c << 6);
        __syncthreads();
#pragma unroll
        for (int p = 0; p < 2; ++p) {
            const int r  = (p << 5) + (tid >> 3);
            const int sg = (tid & 7) << 3;
            const int jc = min(max(j0 + r, 0), S_LEN - 1);
            *(uint4*)&K_lds[r][sg] =
                *(const uint4*)(Kg + (size_t)(b * S_LEN + jc) * HDIM + h * DH + sg);
            const int js = min(max(j0 + sg, 0), S_LEN - 8);
            *(uint4*)&V_lds[r][sg] =
                *(const uint4*)(Vt + ((size_t)((b * NH + h) * DH + r)) * S_LEN + js);
        }
        __syncthreads();

#pragma unroll
        for (int ks = 0; ks < 4; ++ks) {
            const bf16x8 kf0 = ldfrag(&K_lds[(ks << 4) + qcol][quad * 8]);
            const bf16x8 kf1 = ldfrag(&K_lds[(ks << 4) + qcol][32 + quad * 8]);
            f32x4 z = (f32x4){0.f, 0.f, 0.f, 0.f};
            z = __builtin_amdgcn_mfma_f32_16x16x32_bf16(kf0, qf0, z, 0, 0, 0);
            z = __builtin_amdgcn_mfma_f32_16x16x32_bf16(kf1, qf1, z, 0, 0, 0);
            unsigned short pb[4];
#pragma unroll
            for (int r = 0; r < 4; ++r) {
                const int j  = j0 + (ks << 4) + (quad << 2) + r;
                const int dd = (tq0 + qcol) - j;
                const bool ok = (j >= 0) && (j < S_LEN) && (dd <= HALF_W) && (dd >= -HALF_W);
                const float s = z[r] * 0.125f - slope * fabsf((float)dd);
                const float p = ok ? __expf(s - 12.0f) : 0.0f;
                lsum += p;
                pb[r] = f2b(p);
            }
            uint2 pk;
            pk.x = (unsigned int)pb[0] | ((unsigned int)pb[1] << 16);
            pk.y = (unsigned int)pb[2] | ((unsigned int)pb[3] << 16);
            *(uint2*)&P_lds[w][qcol][(ks << 4) + (quad << 2)] = pk;
        }

        const bf16x8 pf0 = ldfrag(&P_lds[w][qcol][quad * 8]);
        const bf16x8 pf1 = ldfrag(&P_lds[w][qcol][32 + quad * 8]);
#pragma unroll
        for (int ds = 0; ds < 4; ++ds) {
            const bf16x8 vf0 = ldfrag(&V_lds[(ds << 4) + qcol][quad * 8]);
            const bf16x8 vf1 = ldfrag(&V_lds[(ds << 4) + qcol][32 + quad * 8]);
            Oacc[ds] = __builtin_amdgcn_mfma_f32_16x16x32_bf16(vf0, pf0, Oacc[ds], 0, 0, 0);
            Oacc[ds] = __builtin_amdgcn_mfma_f32_16x16x32_bf16(vf1, pf1, Oacc[ds], 0, 0, 0);
        }
    }

    lsum += __shfl_xor(lsum, 16, 64);
    lsum += __shfl_xor(lsum, 32, 64);
    const float rz = 1.0f / lsum;

    unsigned short* obase = O + (size_t)(b * S_LEN + tq0 + qcol) * HDIM + h * DH;
#pragma unroll
    for (int ds = 0; ds < 4; ++ds) {
        uint2 pk;
        pk.x = (unsigned int)f2b(Oacc[ds][0] * rz) | ((unsigned int)f2b(Oacc[ds][1] * rz) << 16);
        pk.y = (unsigned int)f2b(Oacc[ds][2] * rz) | ((unsigned int)f2b(Oacc[ds][3] * rz) << 16);
        *(uint2*)(obase + (ds << 4) + (quad << 2)) = pk;
    }
}

// ---------- launch ----------
extern "C" void kernel_launch(void* const* d_in, const int* in_sizes, int n_in,
                              void* d_out, int out_size, void* d_ws, size_t ws_size,
                              hipStream_t stream) {
    const void* xq  = d_in[0];
    const void* xkv = d_in[1];
    const void* wq  = d_in[2];
    const void* wk  = d_in[3];
    const void* wv  = d_in[4];
    const void* wo  = d_in[5];

    int* flag = (int*)d_ws;
    unsigned short* Qb  = (unsigned short*)((char*)d_ws + 256);
    unsigned short* Kb  = Qb  + (size_t)M_ROWS * HDIM;
    unsigned short* Vtb = Kb  + (size_t)M_ROWS * HDIM;
    unsigned short* Wt  = Vtb + (size_t)M_ROWS * HDIM;
    unsigned short* Wto = Wt + (size_t)3 * EMB * EMB;
    unsigned short* Xc  = (unsigned short*)d_out;   // dead until gemm_out writes it

    detect_dtype<<<1, 256, 0, stream>>>((const unsigned short*)xq, flag);
    transpose_w<<<dim3(16, 16, 4), 256, 0, stream>>>(wq, wk, wv, wo, Wt, flag);
    convert_in<<<dim3(2048, 2), 256, 0, stream>>>(xq, xkv, Xc, flag);

    gemm_qkv<<<1536, 256, 0, stream>>>(xq, xkv, Xc, Wt, Qb, Kb, Vtb, flag);
    attn_mfma<<<BATCH * NH * (S_LEN / 64), 256, 0, stream>>>(Qb, Kb, Vtb, Qb);
    gemm_out<<<512, 256, 0, stream>>>(Qb, Wto, d_out, flag);
}

// Round 10
// 165.685 us; speedup vs baseline: 1.5366x; 1.0313x over previous
//
#include <hip/hip_runtime.h>

// Problem: B=2, S=4096, E=512, H=8, D=64, window 512->513 (HALF=256)
#define S_LEN  4096
#define NH     8
#define DH     64
#define EMB    512
#define HDIM   512
#define HALF_W 256
#define BATCH  2
#define M_ROWS (BATCH * S_LEN)  // 8192

typedef __attribute__((ext_vector_type(8))) short bf16x8;
typedef __attribute__((ext_vector_type(4))) float f32x4;

// ---------- bf16 helpers ----------
__device__ __forceinline__ float b2f(unsigned short u) {
    union { unsigned int i; float f; } v; v.i = ((unsigned int)u) << 16; return v.f;
}
__device__ __forceinline__ unsigned short f2b(float f) {
    unsigned int x = __float_as_uint(f);
    unsigned int r = (x + 0x7fffu + ((x >> 16) & 1u)) >> 16;   // RNE
    return (unsigned short)r;
}
__device__ __forceinline__ void unpack2(unsigned int u, float* d) {
    d[0] = b2f((unsigned short)(u & 0xffffu));
    d[1] = b2f((unsigned short)(u >> 16));
}
union FragU { uint4 u; bf16x8 f; };
__device__ __forceinline__ bf16x8 ldfrag(const unsigned short* p) {
    FragU x; x.u = *(const uint4*)p; return x.f;
}

// ---------- async global->LDS, 16B per lane (m97 pattern) ----------
__device__ __forceinline__ void async16(const unsigned short* g, unsigned short* l) {
    __builtin_amdgcn_global_load_lds(
        (__attribute__((address_space(1))) void*)const_cast<unsigned short*>(g),
        (__attribute__((address_space(3))) void*)l, 16, 0, 0);
}

// ---------- inline dtype detect (per-block; deterministic, L2-hot 4KB scan) ----------
// fp32-as-u16 stream: ~22% of even u16s decode to |x|>1e6 or NaN; bf16 N(0,1) never.
__device__ __forceinline__ int detect_flag(const unsigned short* __restrict__ xq) {
    __shared__ int s_flag;
    if (threadIdx.x == 0) s_flag = 0;
    __syncthreads();
    uint4 u = *(const uint4*)(xq + threadIdx.x * 8);
    const unsigned short* us = (const unsigned short*)&u;
    int bad = 0;
#pragma unroll
    for (int i = 0; i < 8; ++i) {
        float v = b2f(us[i]);
        if (!(fabsf(v) < 1.0e6f)) bad = 1;
    }
    if (__any(bad) && (threadIdx.x & 63) == 0) atomicOr(&s_flag, 1);
    __syncthreads();
    return s_flag;   // 1 = fp32 inputs, 0 = bf16 inputs
}

// ---------- fused prep: weight transpose->Wt[n][k] bf16  +  input fp32->bf16 convert ----------
// grid.x = 1024 (weights: 4 x 256) + 4096 (convert: 2 x 2048)
__global__ __launch_bounds__(256) void prep(
    const void* __restrict__ xq, const void* __restrict__ xkv,
    const void* __restrict__ w0, const void* __restrict__ w1,
    const void* __restrict__ w2, const void* __restrict__ w3,
    unsigned short* __restrict__ Wt, unsigned short* __restrict__ Xc)
{
    const int flag = detect_flag((const unsigned short*)xq);
    const int blk = blockIdx.x;
    if (blk < 1024) {
        // weight transpose: z = blk>>8, 16x16 grid of 32x32 tiles
        __shared__ float t[32][33];
        const int z = blk >> 8, idx = blk & 255;
        const void* src = (z == 0) ? w0 : (z == 1) ? w1 : (z == 2) ? w2 : w3;
        unsigned short* dst = Wt + (size_t)z * EMB * EMB;
        const int n0 = (idx & 15) << 5, k0 = (idx >> 4) << 5;
        const int kk = threadIdx.x >> 3;
        const int n4 = (threadIdx.x & 7) << 2;
        if (flag) {
            float4 v = *(const float4*)((const float*)src + (size_t)(k0 + kk) * EMB + n0 + n4);
            t[kk][n4] = v.x; t[kk][n4 + 1] = v.y; t[kk][n4 + 2] = v.z; t[kk][n4 + 3] = v.w;
        } else {
            uint2 u = *(const uint2*)((const unsigned short*)src + (size_t)(k0 + kk) * EMB + n0 + n4);
            unpack2(u.x, &t[kk][n4]); unpack2(u.y, &t[kk][n4 + 2]);
        }
        __syncthreads();
        const int nn = threadIdx.x >> 3;
        const int ks = (threadIdx.x & 7) << 2;
        uint2 pk;
        pk.x = (unsigned int)f2b(t[ks + 0][nn]) | ((unsigned int)f2b(t[ks + 1][nn]) << 16);
        pk.y = (unsigned int)f2b(t[ks + 2][nn]) | ((unsigned int)f2b(t[ks + 3][nn]) << 16);
        *(uint2*)(dst + (size_t)(n0 + nn) * EMB + k0 + ks) = pk;
    } else {
        // input convert (only needed in fp32 world)
        if (!flag) return;
        const int idx = blk - 1024;
        const int z = idx >> 11;                 // 0 = xq, 1 = xkv
        const float* src = (const float*)(z ? xkv : xq);
        unsigned short* dst = Xc + (size_t)z * M_ROWS * EMB;
        const size_t base = ((size_t)(idx & 2047) * 256 + threadIdx.x) * 8;
        float4 a = *(const float4*)(src + base);
        float4 b = *(const float4*)(src + base + 4);
        uint4 pk;
        pk.x = (unsigned int)f2b(a.x) | ((unsigned int)f2b(a.y) << 16);
        pk.y = (unsigned int)f2b(a.z) | ((unsigned int)f2b(a.w) << 16);
        pk.z = (unsigned int)f2b(b.x) | ((unsigned int)f2b(b.y) << 16);
        pk.w = (unsigned int)f2b(b.z) | ((unsigned int)f2b(b.w) << 16);
        *(uint4*)(dst + base) = pk;
    }
}

// ---------- MFMA GEMM core v4 (unchanged): 128x64, BK=64, async + XOR swizzle ----------
__device__ __forceinline__ void mgemm_core4(
    const unsigned short* __restrict__ A, const unsigned short* __restrict__ Bt,
    int m0, f32x4 (*acc)[2],
    unsigned short (*A_lds)[64], unsigned short (*B_lds)[64])
{
    const int tid  = threadIdx.x;
    const int lane = tid & 63;
    const int w    = tid >> 6;
    const int wm   = (w >> 1) << 6;
    const int wn   = (w & 1) << 5;
    const int qcol = lane & 15;
    const int quad = lane >> 4;

    const int srow = tid >> 3;
    const int sp   = tid & 7;

    for (int k0 = 0; k0 < EMB; k0 += 64) {
        __syncthreads();
#pragma unroll
        for (int i = 0; i < 4; ++i) {
            const int row  = (i << 5) + srow;
            const int gcol = ((sp ^ (row & 7)) << 3);
            async16(A + (size_t)(m0 + row) * EMB + k0 + gcol, &A_lds[row][sp << 3]);
        }
#pragma unroll
        for (int i = 0; i < 2; ++i) {
            const int row  = (i << 5) + srow;
            const int gcol = ((sp ^ (row & 7)) << 3);
            async16(Bt + (size_t)row * EMB + k0 + gcol, &B_lds[row][sp << 3]);
        }
        __syncthreads();

#pragma unroll
        for (int kh = 0; kh < 2; ++kh) {
            bf16x8 af[4], bf[2];
#pragma unroll
            for (int i = 0; i < 4; ++i) {
                const int row = wm + (i << 4) + qcol;
                const int p   = ((kh << 2) + quad) ^ (row & 7);
                af[i] = ldfrag(&A_lds[row][p << 3]);
            }
#pragma unroll
            for (int j = 0; j < 2; ++j) {
                const int row = wn + (j << 4) + qcol;
                const int p   = ((kh << 2) + quad) ^ (row & 7);
                bf[j] = ldfrag(&B_lds[row][p << 3]);
            }
#pragma unroll
            for (int i = 0; i < 4; ++i)
#pragma unroll
                for (int j = 0; j < 2; ++j)
                    acc[i][j] = __builtin_amdgcn_mfma_f32_16x16x32_bf16(af[i], bf[j], acc[i][j], 0, 0, 0);
        }
    }
}

// fused QKV: 1536 blocks; XCD-grouped (xcd owns 8 m-tiles x all 24 n-tiles)
__global__ __launch_bounds__(256) void gemm_qkv(
    const void* __restrict__ xq, const void* __restrict__ xkv,
    const unsigned short* __restrict__ Xc, const unsigned short* __restrict__ Wt,
    unsigned short* __restrict__ Qb, unsigned short* __restrict__ Kb,
    unsigned short* __restrict__ Vtb)
{
    const int flag = detect_flag((const unsigned short*)xq);
    __shared__ __align__(16) unsigned short A_lds[128][64];
    __shared__ __align__(16) unsigned short B_lds[64][64];
    const int blk = blockIdx.x;
    const int xcd = blk & 7, idx = blk >> 3;
    const int mi = idx / 24, ni = idx - mi * 24;
    const int m0 = ((xcd << 3) + mi) << 7;
    const int n0 = ni << 6;

    const unsigned short* A;
    if (flag) A = Xc + (n0 < 512 ? (size_t)0 : (size_t)M_ROWS * EMB);
    else      A = (const unsigned short*)(n0 < 512 ? xq : xkv);
    const unsigned short* Bt = Wt + (size_t)n0 * EMB;

    f32x4 acc[4][2];
#pragma unroll
    for (int i = 0; i < 4; ++i)
#pragma unroll
        for (int j = 0; j < 2; ++j) acc[i][j] = (f32x4){0.f, 0.f, 0.f, 0.f};

    mgemm_core4(A, Bt, m0, acc, A_lds, B_lds);

    const int lane = threadIdx.x & 63, w = threadIdx.x >> 6;
    const int wm = (w >> 1) << 6, wn = (w & 1) << 5;
    const int qcol = lane & 15, quad = lane >> 4;
    const int mode = n0 >> 9;   // 0=Q, 1=K, 2=V
#pragma unroll
    for (int ms = 0; ms < 4; ++ms)
#pragma unroll
        for (int ns = 0; ns < 2; ++ns)
#pragma unroll
            for (int r = 0; r < 4; ++r) {
                const int m = m0 + wm + (ms << 4) + (quad << 2) + r;
                const int n = n0 + wn + (ns << 4) + qcol;
                const unsigned short us = f2b(acc[ms][ns][r]);
                if (mode == 0) {
                    Qb[(size_t)m * HDIM + n] = us;
                } else if (mode == 1) {
                    Kb[(size_t)m * HDIM + (n - 512)] = us;
                } else {
                    const int hd = n - 1024;
                    const int bb = m >> 12, s = m & (S_LEN - 1);
                    const int hh = hd >> 6, d = hd & 63;
                    Vtb[((size_t)((bb * NH + hh) * DH + d)) * S_LEN + s] = us;
                }
            }
}

// output projection: 512 blocks; XCD-grouped
__global__ __launch_bounds__(256) void gemm_out(
    const void* __restrict__ xq,
    const unsigned short* __restrict__ A, const unsigned short* __restrict__ Bt,
    void* __restrict__ C)
{
    const int flag = detect_flag((const unsigned short*)xq);
    __shared__ __align__(16) unsigned short A_lds[128][64];
    __shared__ __align__(16) unsigned short B_lds[64][64];
    const int blk = blockIdx.x;
    const int xcd = blk & 7, idx = blk >> 3;
    const int mi = idx >> 3, ni = idx & 7;
    const int m0 = ((xcd << 3) + mi) << 7;
    const int n0 = ni << 6;

    f32x4 acc[4][2];
#pragma unroll
    for (int i = 0; i < 4; ++i)
#pragma unroll
        for (int j = 0; j < 2; ++j) acc[i][j] = (f32x4){0.f, 0.f, 0.f, 0.f};

    mgemm_core4(A, Bt + (size_t)n0 * EMB, m0, acc, A_lds, B_lds);

    const int lane = threadIdx.x & 63, w = threadIdx.x >> 6;
    const int wm = (w >> 1) << 6, wn = (w & 1) << 5;
    const int qcol = lane & 15, quad = lane >> 4;
#pragma unroll
    for (int ms = 0; ms < 4; ++ms)
#pragma unroll
        for (int ns = 0; ns < 2; ++ns)
#pragma unroll
            for (int r = 0; r < 4; ++r) {
                const int m = m0 + wm + (ms << 4) + (quad << 2) + r;
                const int n = n0 + wn + (ns << 4) + qcol;
                const float v = acc[ms][ns][r];
                if (flag) ((float*)C)[(size_t)m * HDIM + n] = v;
                else      ((unsigned short*)C)[(size_t)m * HDIM + n] = f2b(v);
            }
}

// ---------- MFMA flash attention v3: 128-query tile, async+swizzled K/V staging ----------
// S^T = mfma(K,Q), O^T = mfma(V,P) — layouts as v2 (HW-verified). Fixed-max exp(s-12).
// 10 key-chunks of 64 cover [t0-256, t0+383]. Wave w: queries t0+32w .. +31 (2 subtiles).
__global__ __launch_bounds__(256) void attn_mfma(
    const unsigned short* __restrict__ Q,
    const unsigned short* __restrict__ Kg,
    const unsigned short* __restrict__ Vt,
    unsigned short* __restrict__ O)
{
    __shared__ __align__(16) unsigned short K_lds[64][64];    // [key][d], XOR-swizzled segs
    __shared__ __align__(16) unsigned short V_lds[64][64];    // [d][key], XOR-swizzled segs
    __shared__ __align__(16) unsigned short P_lds[4][32][72]; // per-wave [q][key]

    const int tid  = threadIdx.x;
    const int lane = tid & 63;
    const int w    = tid >> 6;
    const int blk  = blockIdx.x;
    const int bh   = blk >> 5;
    const int r5   = blk & 31;
    const int tile = ((r5 & 7) << 2) | (r5 >> 3);   // xcd = blk%8 owns 4 contiguous tiles
    const int h    = bh & (NH - 1);
    const int b    = bh >> 3;
    const int t0   = tile << 7;
    const int tq0  = t0 + (w << 5);                 // wave's 32 queries

    const int qcol = lane & 15;
    const int quad = lane >> 4;
    const float slope = 1.0f / (float)(2 << h);     // 2^-(h+1)

    bf16x8 qf[2][2];
#pragma unroll
    for (int qs = 0; qs < 2; ++qs) {
        const unsigned short* qrow =
            Q + (size_t)(b * S_LEN + tq0 + (qs << 4) + qcol) * HDIM + h * DH;
        qf[qs][0] = ldfrag(qrow + quad * 8);
        qf[qs][1] = ldfrag(qrow + 32 + quad * 8);
    }

    f32x4 Oacc[2][4];
#pragma unroll
    for (int qs = 0; qs < 2; ++qs)
#pragma unroll
        for (int i = 0; i < 4; ++i) Oacc[qs][i] = (f32x4){0.f, 0.f, 0.f, 0.f};
    float lsum[2] = {0.f, 0.f};

    const int srow = tid >> 3;   // 0..31
    const int sp   = tid & 7;

    for (int c = 0; c < 10; ++c) {
        const int j0 = t0 - HALF_W + (c << 6);
        __syncthreads();
#pragma unroll
        for (int i = 0; i < 2; ++i) {
            const int row  = (i << 5) + srow;           // 0..63
            const int gseg = (sp ^ (row & 7)) << 3;
            const int jc = min(max(j0 + row, 0), S_LEN - 1);
            async16(Kg + (size_t)(b * S_LEN + jc) * HDIM + h * DH + gseg,
                    &K_lds[row][sp << 3]);
            const int js = min(max(j0 + gseg, 0), S_LEN - 8);
            async16(Vt + ((size_t)((b * NH + h) * DH + row)) * S_LEN + js,
                    &V_lds[row][sp << 3]);
        }
        __syncthreads();

        // S^T + mask/exp -> P_lds
#pragma unroll
        for (int qs = 0; qs < 2; ++qs) {
#pragma unroll
            for (int ks = 0; ks < 4; ++ks) {
                const int krow = (ks << 4) + qcol;
                const bf16x8 kf0 = ldfrag(&K_lds[krow][(quad ^ (krow & 7)) << 3]);
                const bf16x8 kf1 = ldfrag(&K_lds[krow][((4 + quad) ^ (krow & 7)) << 3]);
                f32x4 z = (f32x4){0.f, 0.f, 0.f, 0.f};
                z = __builtin_amdgcn_mfma_f32_16x16x32_bf16(kf0, qf[qs][0], z, 0, 0, 0);
                z = __builtin_amdgcn_mfma_f32_16x16x32_bf16(kf1, qf[qs][1], z, 0, 0, 0);
                unsigned short pb[4];
#pragma unroll
                for (int r = 0; r < 4; ++r) {
                    const int j  = j0 + (ks << 4) + (quad << 2) + r;
                    const int dd = (tq0 + (qs << 4) + qcol) - j;
                    const bool ok = (j >= 0) && (j < S_LEN) && (dd <= HALF_W) && (dd >= -HALF_W);
                    const float s = z[r] * 0.125f - slope * fabsf((float)dd);
                    const float p = ok ? __expf(s - 12.0f) : 0.0f;
                    lsum[qs] += p;
                    pb[r] = f2b(p);
                }
                uint2 pk;
                pk.x = (unsigned int)pb[0] | ((unsigned int)pb[1] << 16);
                pk.y = (unsigned int)pb[2] | ((unsigned int)pb[3] << 16);
                *(uint2*)&P_lds[w][(qs << 4) + qcol][(ks << 4) + (quad << 2)] = pk;
            }
        }
        // O^T += V^T P^T
#pragma unroll
        for (int qs = 0; qs < 2; ++qs) {
            const bf16x8 pf0 = ldfrag(&P_lds[w][(qs << 4) + qcol][quad * 8]);
            const bf16x8 pf1 = ldfrag(&P_lds[w][(qs << 4) + qcol][32 + quad * 8]);
#pragma unroll
            for (int ds = 0; ds < 4; ++ds) {
                const int vrow = (ds << 4) + qcol;
                const bf16x8 vf0 = ldfrag(&V_lds[vrow][(quad ^ (vrow & 7)) << 3]);
                const bf16x8 vf1 = ldfrag(&V_lds[vrow][((4 + quad) ^ (vrow & 7)) << 3]);
                Oacc[qs][ds] = __builtin_amdgcn_mfma_f32_16x16x32_bf16(vf0, pf0, Oacc[qs][ds], 0, 0, 0);
                Oacc[qs][ds] = __builtin_amdgcn_mfma_f32_16x16x32_bf16(vf1, pf1, Oacc[qs][ds], 0, 0, 0);
            }
        }
    }

#pragma unroll
    for (int qs = 0; qs < 2; ++qs) {
        float l = lsum[qs];
        l += __shfl_xor(l, 16, 64);
        l += __shfl_xor(l, 32, 64);
        const float rz = 1.0f / l;
        unsigned short* obase =
            O + (size_t)(b * S_LEN + tq0 + (qs << 4) + qcol) * HDIM + h * DH;
#pragma unroll
        for (int ds = 0; ds < 4; ++ds) {
            uint2 pk;
            pk.x = (unsigned int)f2b(Oacc[qs][ds][0] * rz) |
                   ((unsigned int)f2b(Oacc[qs][ds][1] * rz) << 16);
            pk.y = (unsigned int)f2b(Oacc[qs][ds][2] * rz) |
                   ((unsigned int)f2b(Oacc[qs][ds][3] * rz) << 16);
            *(uint2*)(obase + (ds << 4) + (quad << 2)) = pk;
        }
    }
}

// ---------- launch: 4 kernels ----------
extern "C" void kernel_launch(void* const* d_in, const int* in_sizes, int n_in,
                              void* d_out, int out_size, void* d_ws, size_t ws_size,
                              hipStream_t stream) {
    const void* xq  = d_in[0];
    const void* xkv = d_in[1];
    const void* wq  = d_in[2];
    const void* wk  = d_in[3];
    const void* wv  = d_in[4];
    const void* wo  = d_in[5];

    // ws: [pad 256B][Q/A 8MB][K 8MB][Vt 8MB][Wt 4x0.5MB]; bf16 input staging in d_out
    unsigned short* Qb  = (unsigned short*)((char*)d_ws + 256);
    unsigned short* Kb  = Qb  + (size_t)M_ROWS * HDIM;
    unsigned short* Vtb = Kb  + (size_t)M_ROWS * HDIM;
    unsigned short* Wt  = Vtb + (size_t)M_ROWS * HDIM;
    unsigned short* Wto = Wt + (size_t)3 * EMB * EMB;
    unsigned short* Xc  = (unsigned short*)d_out;   // dead until gemm_out writes it

    prep<<<1024 + 4096, 256, 0, stream>>>(xq, xkv, wq, wk, wv, wo, Wt, Xc);
    gemm_qkv<<<1536, 256, 0, stream>>>(xq, xkv, Xc, Wt, Qb, Kb, Vtb);
    attn_mfma<<<BATCH * NH * (S_LEN / 128), 256, 0, stream>>>(Qb, Kb, Vtb, Qb);
    gemm_out<<<512, 256, 0, stream>>>(xq, Qb, Wto, d_out);
}